// Round 9
// baseline (112.743 us; speedup 1.0000x reference)
//
#include <hip/hip_runtime.h>
#include <math.h>

// PointsGeneration: elementwise sigmoid + threshold-gated regression concat.
//
// R8 = R7 group-split structure with WPX=4096: tests 16 KB contiguous runs
// at 4 waves/SIMD (R5's 16 KB probe was confounded by 1 wave/SIMD; R4->R7
// showed occupancy 2->8 is only worth ~1 us, so run length needs a clean
// test at >=4 waves/SIMD).
//   g0: 4 score planes -> sigmoid -> ch 0..3 (one plane at a time)
//   g1: text+head masks -> gate reg_head -> ch 4..7
//   g2: text+tail masks -> gate reg_tail -> ch 8..11
//   g3: bond mask -> gate reg_bond -> ch 12..15
// Ledger: 1KB=120, 8KB@2w=107.5, 16KB@1w=113.5, pair=114.8, 8KB@8w=106.3.

typedef float f32x4 __attribute__((ext_vector_type(4)));
typedef unsigned long long u64;

static __device__ __forceinline__ float sigf(float x) {
    // Accurate fp32 sigmoid (expf, not __expf): threshold comparisons sit on
    // the sigmoid value; match the numpy fp32 reference to avoid mask flips.
    return 1.0f / (1.0f + expf(-x));
}

static __device__ __forceinline__ f32x4 ld4(const float* p) {
    return *reinterpret_cast<const f32x4*>(p);
}
static __device__ __forceinline__ void st4(float* p, f32x4 v) {
    *reinterpret_cast<f32x4*>(p) = v;
}

// sigmoid(plane window) -> store (16 KB run in, 16 KB run out)
static __device__ __forceinline__ void plane_sig(
    const float* __restrict__ src, float* __restrict__ dst, int base)
{
    f32x4 v[16];
#pragma unroll
    for (int j = 0; j < 16; ++j) v[j] = ld4(src + base + j * 256);
#pragma unroll
    for (int j = 0; j < 16; ++j)
#pragma unroll
        for (int k = 0; k < 4; ++k) v[j][k] = sigf(v[j][k]);
#pragma unroll
    for (int j = 0; j < 16; ++j) st4(dst + base + j * 256, v[j]);
}

// 64-bit mask of (sigmoid(window) > thr), values discarded
static __device__ __forceinline__ u64 mask_of(
    const float* __restrict__ src, float thr, int base)
{
    f32x4 v[16];
#pragma unroll
    for (int j = 0; j < 16; ++j) v[j] = ld4(src + base + j * 256);
    u64 m = 0;
#pragma unroll
    for (int j = 0; j < 16; ++j)
#pragma unroll
        for (int k = 0; k < 4; ++k)
            if (sigf(v[j][k]) > thr) m |= 1ull << (4 * j + k);
    return m;
}

// gate one regression channel window by mask (16 KB run in, 16 KB run out)
static __device__ __forceinline__ void gate(
    const float* __restrict__ src, float* __restrict__ dst,
    u64 m, int base)
{
    f32x4 v[16];
#pragma unroll
    for (int j = 0; j < 16; ++j) v[j] = ld4(src + base + j * 256);
#pragma unroll
    for (int j = 0; j < 16; ++j)
#pragma unroll
        for (int k = 0; k < 4; ++k)
            v[j][k] = ((m >> (4 * j + k)) & 1ull) ? v[j][k] : 0.0f;
#pragma unroll
    for (int j = 0; j < 16; ++j) st4(dst + base + j * 256, v[j]);
}

__global__ __launch_bounds__(256) void points_gen_kernel(
    const float* __restrict__ p_text,
    const float* __restrict__ p_head,
    const float* __restrict__ p_tail,
    const float* __restrict__ p_bond,
    const float* __restrict__ p_rh,
    const float* __restrict__ p_rt,
    const float* __restrict__ p_rb,
    float* __restrict__ out)
{
    constexpr int N = 2048 * 2048;   // pixels per plane
    constexpr int WPX = 4096;        // pixels per wave per plane (16 KB)
    const int lane = threadIdx.x & 63;
    const int g = threadIdx.x >> 6;  // group = wave within block
    const int w = blockIdx.x;        // window index 0..1023
    const int base = w * WPX + lane * 4;   // + j*256 for j in 0..15

    if (g == 0) {
        plane_sig(p_text, out + 0 * N, base);
        plane_sig(p_head, out + 1 * N, base);
        plane_sig(p_tail, out + 2 * N, base);
        plane_sig(p_bond, out + 3 * N, base);
    } else if (g == 1) {
        const u64 m = mask_of(p_text, 0.45f, base) &
                      mask_of(p_head, 0.50f, base);
#pragma unroll
        for (int c = 0; c < 4; ++c)
            gate(p_rh + c * N, out + (4 + c) * N, m, base);
    } else if (g == 2) {
        const u64 m = mask_of(p_text, 0.45f, base) &
                      mask_of(p_tail, 0.50f, base);
#pragma unroll
        for (int c = 0; c < 4; ++c)
            gate(p_rt + c * N, out + (8 + c) * N, m, base);
    } else {
        const u64 m = mask_of(p_bond, 0.50f, base);
#pragma unroll
        for (int c = 0; c < 4; ++c)
            gate(p_rb + c * N, out + (12 + c) * N, m, base);
    }
}

extern "C" void kernel_launch(void* const* d_in, const int* in_sizes, int n_in,
                              void* d_out, int out_size, void* d_ws, size_t ws_size,
                              hipStream_t stream) {
    (void)in_sizes; (void)n_in; (void)out_size; (void)d_ws; (void)ws_size;

    const float* p_text = (const float*)d_in[0];
    const float* p_head = (const float*)d_in[1];
    const float* p_tail = (const float*)d_in[2];
    const float* p_bond = (const float*)d_in[3];
    const float* p_rh   = (const float*)d_in[4];
    const float* p_rt   = (const float*)d_in[5];
    const float* p_rb   = (const float*)d_in[6];
    float* out = (float*)d_out;

    constexpr int N = 2048 * 2048;
    constexpr int WPX = 4096;                  // pixels per wave per plane
    constexpr int blocks = N / WPX;            // 1024 windows, 4 waves each

    points_gen_kernel<<<blocks, 256, 0, stream>>>(
        p_text, p_head, p_tail, p_bond, p_rh, p_rt, p_rb, out);
}

// Round 10
// 110.879 us; speedup vs baseline: 1.0168x; 1.0168x over previous
//
#include <hip/hip_runtime.h>
#include <math.h>

// PointsGeneration: elementwise sigmoid + threshold-gated regression concat.
//
// R9 = R7 (8 KB runs, 4 wave-groups/window, 8 waves/SIMD — best so far at
// 106.3 us) + LDS MASK PASSING: g0 computes all 4 sigmoid planes (it stores
// ch0-3 anyway) and publishes the 3 gate masks to LDS; g1-g3 consume them
// after one __syncthreads instead of RE-READING score planes. Removes the
// 84 MB (+31% read) redundancy — traffic is now the exact 537 MB minimum,
// and every wave does exactly 4 loads + 4 stores (balanced).
// Ledger: 1KB=120, 8KB@2w=107.5, 16KB@1w=113.5, pair=114.8, 8KB@8w=106.3,
//         16KB@4w=112.7.

typedef float f32x4 __attribute__((ext_vector_type(4)));

static __device__ __forceinline__ float sigf(float x) {
    // Accurate fp32 sigmoid (expf, not __expf): threshold comparisons sit on
    // the sigmoid value; match the numpy fp32 reference to avoid mask flips.
    return 1.0f / (1.0f + expf(-x));
}

static __device__ __forceinline__ f32x4 ld4(const float* p) {
    return *reinterpret_cast<const f32x4*>(p);
}
static __device__ __forceinline__ void st4(float* p, f32x4 v) {
    *reinterpret_cast<f32x4*>(p) = v;
}

// sigmoid one score plane's 8 KB window, store it, return 32-bit mask of
// (sigmoid > thr) per pixel (bit 4*j+k for vector j, component k).
static __device__ __forceinline__ unsigned sig_plane_mask(
    const float* __restrict__ src, float* __restrict__ dst,
    float thr, int base)
{
    f32x4 v[8];
#pragma unroll
    for (int j = 0; j < 8; ++j) v[j] = ld4(src + base + j * 256);
    unsigned m = 0;
#pragma unroll
    for (int j = 0; j < 8; ++j) {
#pragma unroll
        for (int k = 0; k < 4; ++k) {
            v[j][k] = sigf(v[j][k]);
            if (v[j][k] > thr) m |= 1u << (4 * j + k);
        }
    }
#pragma unroll
    for (int j = 0; j < 8; ++j) st4(dst + base + j * 256, v[j]);
    return m;
}

// gate one regression channel window by mask (8 KB run in, 8 KB run out)
static __device__ __forceinline__ void gate(
    const float* __restrict__ src, float* __restrict__ dst,
    unsigned m, int base)
{
    f32x4 v[8];
#pragma unroll
    for (int j = 0; j < 8; ++j) v[j] = ld4(src + base + j * 256);
#pragma unroll
    for (int j = 0; j < 8; ++j)
#pragma unroll
        for (int k = 0; k < 4; ++k)
            v[j][k] = ((m >> (4 * j + k)) & 1u) ? v[j][k] : 0.0f;
#pragma unroll
    for (int j = 0; j < 8; ++j) st4(dst + base + j * 256, v[j]);
}

__global__ __launch_bounds__(256) void points_gen_kernel(
    const float* __restrict__ p_text,
    const float* __restrict__ p_head,
    const float* __restrict__ p_tail,
    const float* __restrict__ p_bond,
    const float* __restrict__ p_rh,
    const float* __restrict__ p_rt,
    const float* __restrict__ p_rb,
    float* __restrict__ out)
{
    constexpr int N = 2048 * 2048;   // pixels per plane
    constexpr int WPX = 2048;        // pixels per wave per plane (8 KB)
    __shared__ unsigned msk[3][64];  // head/tail/bond gate masks per lane

    const int lane = threadIdx.x & 63;
    const int g = threadIdx.x >> 6;  // wave-group within block
    const int w = blockIdx.x;        // window index 0..2047
    const int base = w * WPX + lane * 4;   // + j*256 for j in 0..7

    if (g == 0) {
        // score planes: sigmoid + store ch0..3, collect masks once
        const unsigned mt = sig_plane_mask(p_text, out + 0 * N, 0.45f, base);
        const unsigned mh = sig_plane_mask(p_head, out + 1 * N, 0.50f, base);
        const unsigned ml = sig_plane_mask(p_tail, out + 2 * N, 0.50f, base);
        const unsigned mb = sig_plane_mask(p_bond, out + 3 * N, 0.50f, base);
        msk[0][lane] = mh & mt;
        msk[1][lane] = ml & mt;
        msk[2][lane] = mb;
    }
    __syncthreads();
    if (g == 1) {
        const unsigned m = msk[0][lane];
#pragma unroll
        for (int c = 0; c < 4; ++c)
            gate(p_rh + c * N, out + (4 + c) * N, m, base);
    } else if (g == 2) {
        const unsigned m = msk[1][lane];
#pragma unroll
        for (int c = 0; c < 4; ++c)
            gate(p_rt + c * N, out + (8 + c) * N, m, base);
    } else if (g == 3) {
        const unsigned m = msk[2][lane];
#pragma unroll
        for (int c = 0; c < 4; ++c)
            gate(p_rb + c * N, out + (12 + c) * N, m, base);
    }
}

extern "C" void kernel_launch(void* const* d_in, const int* in_sizes, int n_in,
                              void* d_out, int out_size, void* d_ws, size_t ws_size,
                              hipStream_t stream) {
    (void)in_sizes; (void)n_in; (void)out_size; (void)d_ws; (void)ws_size;

    const float* p_text = (const float*)d_in[0];
    const float* p_head = (const float*)d_in[1];
    const float* p_tail = (const float*)d_in[2];
    const float* p_bond = (const float*)d_in[3];
    const float* p_rh   = (const float*)d_in[4];
    const float* p_rt   = (const float*)d_in[5];
    const float* p_rb   = (const float*)d_in[6];
    float* out = (float*)d_out;

    constexpr int N = 2048 * 2048;
    constexpr int WPX = 2048;                  // pixels per wave per plane
    constexpr int blocks = N / WPX;            // 2048 windows, 4 waves each

    points_gen_kernel<<<blocks, 256, 0, stream>>>(
        p_text, p_head, p_tail, p_bond, p_rh, p_rt, p_rb, out);
}

// Round 11
// 109.954 us; speedup vs baseline: 1.0254x; 1.0084x over previous
//
#include <hip/hip_runtime.h>
#include <math.h>

// PointsGeneration: elementwise sigmoid + threshold-gated regression concat.
//
// R10 = R7 (8 KB runs, 4 wave-groups, 8 waves/SIMD, best at 106.3 us) +
// PER-GROUP WINDOW ROTATION: group g processes window (w + g*512) & 2047,
// i.e. a 4 MiB in-plane offset shift per group. Tests the power-of-2 stride
// channel-aliasing theory: all planes are 16 MiB apart, and without rotation
// all 23 concurrent streams hit the SAME in-plane offset -> possible HBM
// channel hotspotting. Rotation decorrelates the 4 groups' offsets while
// keeping every group's planes pixel-aligned (masks stay coherent).
// Ledger: 1KB=120, 8KB@2w=107.5, 16KB@1w=113.5, pair=114.8, 8KB@8w=106.3,
//         16KB@4w=112.7, LDS-mask+barrier=110.9.

typedef float f32x4 __attribute__((ext_vector_type(4)));

static __device__ __forceinline__ float sigf(float x) {
    // Accurate fp32 sigmoid (expf, not __expf): threshold comparisons sit on
    // the sigmoid value; match the numpy fp32 reference to avoid mask flips.
    return 1.0f / (1.0f + expf(-x));
}

static __device__ __forceinline__ f32x4 ld4(const float* p) {
    return *reinterpret_cast<const f32x4*>(p);
}
static __device__ __forceinline__ void st4(float* p, f32x4 v) {
    *reinterpret_cast<f32x4*>(p) = v;
}

// sigmoid(plane window) -> store (8 KB run in, 8 KB run out)
static __device__ __forceinline__ void plane_sig(
    const float* __restrict__ src, float* __restrict__ dst, int base)
{
    f32x4 v[8];
#pragma unroll
    for (int j = 0; j < 8; ++j) v[j] = ld4(src + base + j * 256);
#pragma unroll
    for (int j = 0; j < 8; ++j)
#pragma unroll
        for (int k = 0; k < 4; ++k) v[j][k] = sigf(v[j][k]);
#pragma unroll
    for (int j = 0; j < 8; ++j) st4(dst + base + j * 256, v[j]);
}

// 32-bit mask of (sigmoid(window) > thr), values discarded
static __device__ __forceinline__ unsigned mask_of(
    const float* __restrict__ src, float thr, int base)
{
    f32x4 v[8];
#pragma unroll
    for (int j = 0; j < 8; ++j) v[j] = ld4(src + base + j * 256);
    unsigned m = 0;
#pragma unroll
    for (int j = 0; j < 8; ++j)
#pragma unroll
        for (int k = 0; k < 4; ++k)
            if (sigf(v[j][k]) > thr) m |= 1u << (4 * j + k);
    return m;
}

// gate one regression channel window by mask (8 KB run in, 8 KB run out)
static __device__ __forceinline__ void gate(
    const float* __restrict__ src, float* __restrict__ dst,
    unsigned m, int base)
{
    f32x4 v[8];
#pragma unroll
    for (int j = 0; j < 8; ++j) v[j] = ld4(src + base + j * 256);
#pragma unroll
    for (int j = 0; j < 8; ++j)
#pragma unroll
        for (int k = 0; k < 4; ++k)
            v[j][k] = ((m >> (4 * j + k)) & 1u) ? v[j][k] : 0.0f;
#pragma unroll
    for (int j = 0; j < 8; ++j) st4(dst + base + j * 256, v[j]);
}

__global__ __launch_bounds__(256) void points_gen_kernel(
    const float* __restrict__ p_text,
    const float* __restrict__ p_head,
    const float* __restrict__ p_tail,
    const float* __restrict__ p_bond,
    const float* __restrict__ p_rh,
    const float* __restrict__ p_rt,
    const float* __restrict__ p_rb,
    float* __restrict__ out)
{
    constexpr int N = 2048 * 2048;   // pixels per plane
    constexpr int WPX = 2048;        // pixels per wave per plane (8 KB)
    const int lane = threadIdx.x & 63;
    const int gwave = blockIdx.x * 4 + (threadIdx.x >> 6);  // 0..8191
    const int g = gwave & 3;         // group
    // Per-group window rotation: +512 windows (4 MiB) per group decorrelates
    // the concurrent in-plane offsets of the 4 groups across HBM channels.
    const int w = ((gwave >> 2) + g * 512) & 2047;
    const int base = w * WPX + lane * 4;   // + j*256 for j in 0..7

    if (g == 0) {
        plane_sig(p_text, out + 0 * N, base);
        plane_sig(p_head, out + 1 * N, base);
        plane_sig(p_tail, out + 2 * N, base);
        plane_sig(p_bond, out + 3 * N, base);
    } else if (g == 1) {
        const unsigned m = mask_of(p_text, 0.45f, base) &
                           mask_of(p_head, 0.50f, base);
#pragma unroll
        for (int c = 0; c < 4; ++c)
            gate(p_rh + c * N, out + (4 + c) * N, m, base);
    } else if (g == 2) {
        const unsigned m = mask_of(p_text, 0.45f, base) &
                           mask_of(p_tail, 0.50f, base);
#pragma unroll
        for (int c = 0; c < 4; ++c)
            gate(p_rt + c * N, out + (8 + c) * N, m, base);
    } else {
        const unsigned m = mask_of(p_bond, 0.50f, base);
#pragma unroll
        for (int c = 0; c < 4; ++c)
            gate(p_rb + c * N, out + (12 + c) * N, m, base);
    }
}

extern "C" void kernel_launch(void* const* d_in, const int* in_sizes, int n_in,
                              void* d_out, int out_size, void* d_ws, size_t ws_size,
                              hipStream_t stream) {
    (void)in_sizes; (void)n_in; (void)out_size; (void)d_ws; (void)ws_size;

    const float* p_text = (const float*)d_in[0];
    const float* p_head = (const float*)d_in[1];
    const float* p_tail = (const float*)d_in[2];
    const float* p_bond = (const float*)d_in[3];
    const float* p_rh   = (const float*)d_in[4];
    const float* p_rt   = (const float*)d_in[5];
    const float* p_rb   = (const float*)d_in[6];
    float* out = (float*)d_out;

    constexpr int N = 2048 * 2048;
    constexpr int WPX = 2048;                        // pixels per wave per plane
    constexpr int windows = N / WPX;                 // 2048
    constexpr int waves = windows * 4;               // 8192 (4 groups)
    constexpr int blocks = waves / 4;                // 2048 blocks x 4 waves

    points_gen_kernel<<<blocks, 256, 0, stream>>>(
        p_text, p_head, p_tail, p_bond, p_rh, p_rt, p_rb, out);
}

// Round 12
// 107.325 us; speedup vs baseline: 1.0505x; 1.0245x over previous
//
#include <hip/hip_runtime.h>
#include <math.h>

// PointsGeneration: elementwise sigmoid + threshold-gated regression concat.
//
// R11 = exact revert to R7, the measured best (106.3 us = 5.05 TB/s, 80% of
// the 2-stream copy ceiling). 4 wave-groups per block, SAME window per block
// (g1/g2 score re-reads are L2-hot behind g0 — R10 proved this coupling is
// load-bearing), 8 KB contiguous runs per stream visit (run-length curve
// peaks here), 8 waves/SIMD.
//   g0: 4 score planes -> sigmoid -> ch 0..3
//   g1: text+head masks -> gate reg_head -> ch 4..7
//   g2: text+tail masks -> gate reg_tail -> ch 8..11
//   g3: bond mask -> gate reg_bond -> ch 12..15
// Final ledger: 1KB=120, NT=122.3, 8KB@2w=107.5, 16KB@1w=113.5,
//   pair-batch=114.8, 8KB@8w=106.3 (BEST), 16KB@4w=112.7,
//   LDS-mask+barrier=110.9, rotated-groups=110.0.

typedef float f32x4 __attribute__((ext_vector_type(4)));

static __device__ __forceinline__ float sigf(float x) {
    // Accurate fp32 sigmoid (expf, not __expf): threshold comparisons sit on
    // the sigmoid value; match the numpy fp32 reference to avoid mask flips.
    return 1.0f / (1.0f + expf(-x));
}

static __device__ __forceinline__ f32x4 ld4(const float* p) {
    return *reinterpret_cast<const f32x4*>(p);
}
static __device__ __forceinline__ void st4(float* p, f32x4 v) {
    *reinterpret_cast<f32x4*>(p) = v;
}

// sigmoid(plane window) -> store (8 KB run in, 8 KB run out)
static __device__ __forceinline__ void plane_sig(
    const float* __restrict__ src, float* __restrict__ dst, int base)
{
    f32x4 v[8];
#pragma unroll
    for (int j = 0; j < 8; ++j) v[j] = ld4(src + base + j * 256);
#pragma unroll
    for (int j = 0; j < 8; ++j)
#pragma unroll
        for (int k = 0; k < 4; ++k) v[j][k] = sigf(v[j][k]);
#pragma unroll
    for (int j = 0; j < 8; ++j) st4(dst + base + j * 256, v[j]);
}

// 32-bit mask of (sigmoid(window) > thr), values discarded
static __device__ __forceinline__ unsigned mask_of(
    const float* __restrict__ src, float thr, int base)
{
    f32x4 v[8];
#pragma unroll
    for (int j = 0; j < 8; ++j) v[j] = ld4(src + base + j * 256);
    unsigned m = 0;
#pragma unroll
    for (int j = 0; j < 8; ++j)
#pragma unroll
        for (int k = 0; k < 4; ++k)
            if (sigf(v[j][k]) > thr) m |= 1u << (4 * j + k);
    return m;
}

// gate one regression channel window by mask (8 KB run in, 8 KB run out)
static __device__ __forceinline__ void gate(
    const float* __restrict__ src, float* __restrict__ dst,
    unsigned m, int base)
{
    f32x4 v[8];
#pragma unroll
    for (int j = 0; j < 8; ++j) v[j] = ld4(src + base + j * 256);
#pragma unroll
    for (int j = 0; j < 8; ++j)
#pragma unroll
        for (int k = 0; k < 4; ++k)
            v[j][k] = ((m >> (4 * j + k)) & 1u) ? v[j][k] : 0.0f;
#pragma unroll
    for (int j = 0; j < 8; ++j) st4(dst + base + j * 256, v[j]);
}

__global__ __launch_bounds__(256) void points_gen_kernel(
    const float* __restrict__ p_text,
    const float* __restrict__ p_head,
    const float* __restrict__ p_tail,
    const float* __restrict__ p_bond,
    const float* __restrict__ p_rh,
    const float* __restrict__ p_rt,
    const float* __restrict__ p_rb,
    float* __restrict__ out)
{
    constexpr int N = 2048 * 2048;   // pixels per plane
    constexpr int WPX = 2048;        // pixels per wave per plane (8 KB)
    const int lane = threadIdx.x & 63;
    const int gwave = blockIdx.x * 4 + (threadIdx.x >> 6);  // 0..8191
    const int g = gwave & 3;         // group; same window's 4 groups share a block
    const int w = gwave >> 2;        // window index 0..2047
    const int base = w * WPX + lane * 4;   // + j*256 for j in 0..7

    if (g == 0) {
        plane_sig(p_text, out + 0 * N, base);
        plane_sig(p_head, out + 1 * N, base);
        plane_sig(p_tail, out + 2 * N, base);
        plane_sig(p_bond, out + 3 * N, base);
    } else if (g == 1) {
        const unsigned m = mask_of(p_text, 0.45f, base) &
                           mask_of(p_head, 0.50f, base);
#pragma unroll
        for (int c = 0; c < 4; ++c)
            gate(p_rh + c * N, out + (4 + c) * N, m, base);
    } else if (g == 2) {
        const unsigned m = mask_of(p_text, 0.45f, base) &
                           mask_of(p_tail, 0.50f, base);
#pragma unroll
        for (int c = 0; c < 4; ++c)
            gate(p_rt + c * N, out + (8 + c) * N, m, base);
    } else {
        const unsigned m = mask_of(p_bond, 0.50f, base);
#pragma unroll
        for (int c = 0; c < 4; ++c)
            gate(p_rb + c * N, out + (12 + c) * N, m, base);
    }
}

extern "C" void kernel_launch(void* const* d_in, const int* in_sizes, int n_in,
                              void* d_out, int out_size, void* d_ws, size_t ws_size,
                              hipStream_t stream) {
    (void)in_sizes; (void)n_in; (void)out_size; (void)d_ws; (void)ws_size;

    const float* p_text = (const float*)d_in[0];
    const float* p_head = (const float*)d_in[1];
    const float* p_tail = (const float*)d_in[2];
    const float* p_bond = (const float*)d_in[3];
    const float* p_rh   = (const float*)d_in[4];
    const float* p_rt   = (const float*)d_in[5];
    const float* p_rb   = (const float*)d_in[6];
    float* out = (float*)d_out;

    constexpr int N = 2048 * 2048;
    constexpr int WPX = 2048;                        // pixels per wave per plane
    constexpr int windows = N / WPX;                 // 2048
    constexpr int waves = windows * 4;               // 8192 (4 groups)
    constexpr int blocks = waves / 4;                // 2048 blocks x 4 waves

    points_gen_kernel<<<blocks, 256, 0, stream>>>(
        p_text, p_head, p_tail, p_bond, p_rh, p_rt, p_rb, out);
}